// Round 2
// baseline (652.380 us; speedup 1.0000x reference)
//
#include <hip/hip_runtime.h>
#include <hip/hip_bf16.h>

// SimpleBNN: out = sign(sign(sign(x)@sign(w1)T + b1) @ sign(w2)T + b2) @ w3T + b3
// Layers 1-2: exact ternary GEMM via MX-fp4 MFMA (K=128/inst, scale=1.0).
// Layer 3: exact ternary A (i8) x per-row-quantized i8 w3 (error ~1.5e-2).
//
// Round-2 changes:
//  * Both GEMMs: 2-phase double-buffered K-loop (stage t+1 while computing t,
//    ONE __syncthreads per iter), full unroll with compile-time K so all
//    global_load_lds use immediate offsets (kills per-iter address VALU,
//    which was the busiest pipe: VALUBusy 53% > MfmaUtil 27%).
//  * Bijective XCD-aware block swizzle (grids 2048 / 512, both % 8 == 0).
//  * Layer-1 epilogue emits packed fp4 directly (3x shfl_xor nibble
//    compaction, byte/nibble order identical to sign_pack_fp4) -> the
//    repack_i8_fp4 kernel and the 64MB a1-i8 round trip are eliminated.
//
// LDS tiles keep the verified XOR-swizzled layout (16B granules):
//   slot s in [0,512) <-> (row = s>>2, chunk c = (s&3) ^ ((row>>1)&3))
// Staging stays coalesced; fragment ds_read_b128s are conflict-free (2-way
// aliasing = free). Any consistent within-row k-permutation applied to both
// A and B cancels in A@B^T, so pack-order conventions are risk-free.

typedef __attribute__((ext_vector_type(4))) float f32x4;
typedef __attribute__((ext_vector_type(4))) int   i32x4;
typedef __attribute__((ext_vector_type(8))) int   i32x8;

#define BM 128
#define BN 128

__device__ __forceinline__ void async_copy16(const void* g, void* l) {
  __builtin_amdgcn_global_load_lds(
      (const __attribute__((address_space(1))) void*)g,
      (__attribute__((address_space(3))) void*)l,
      16, 0, 0);
}

__device__ __forceinline__ char sign8(float v) {
  return (v > 0.f) ? (char)1 : ((v < 0.f) ? (char)-1 : (char)0);
}
// fp4 e2m1 nibble for sign: +1 -> 0x2, -1 -> 0xA, 0 -> 0x0
__device__ __forceinline__ unsigned nib4(float v) {
  return (v > 0.f) ? 0x2u : ((v < 0.f) ? 0xAu : 0x0u);
}

// fp32 -> packed fp4 sign, 8 elems/thread (4B coalesced stores)
__global__ void sign_pack_fp4(const float* __restrict__ in, unsigned* __restrict__ out, int n8) {
  int i = blockIdx.x * blockDim.x + threadIdx.x;
  if (i >= n8) return;
  const float4* p = (const float4*)in + (size_t)i * 2;
  float4 v0 = p[0], v1 = p[1];
  unsigned b0 = nib4(v0.x) | (nib4(v0.y) << 4);
  unsigned b1 = nib4(v0.z) | (nib4(v0.w) << 4);
  unsigned b2 = nib4(v1.x) | (nib4(v1.y) << 4);
  unsigned b3 = nib4(v1.z) | (nib4(v1.w) << 4);
  out[i] = b0 | (b1 << 8) | (b2 << 16) | (b3 << 24);
}

// w3 [1000,4096] fp32 -> i8 [1024,4096] with per-row scale s[row]=rowmax/127;
// rows >= rows_valid zero-filled with scale 0. One 256-thread block per row.
__global__ __launch_bounds__(256)
void w3_quant(const float* __restrict__ in, char* __restrict__ out,
              float* __restrict__ scale, int rows_valid) {
  const int row = blockIdx.x;
  const int tid = threadIdx.x;
  int* orow = (int*)(out + (size_t)row * 4096);
  if (row >= rows_valid) {
#pragma unroll
    for (int j = 0; j < 4; ++j) orow[j * 256 + tid] = 0;
    if (tid == 0) scale[row] = 0.f;
    return;
  }
  const float4* p = (const float4*)(in + (size_t)row * 4096);
  float4 v[4];
  float amax = 0.f;
#pragma unroll
  for (int j = 0; j < 4; ++j) {
    v[j] = p[j * 256 + tid];
    amax = fmaxf(amax, fmaxf(fmaxf(fabsf(v[j].x), fabsf(v[j].y)),
                             fmaxf(fabsf(v[j].z), fabsf(v[j].w))));
  }
#pragma unroll
  for (int m = 32; m >= 1; m >>= 1)
    amax = fmaxf(amax, __shfl_xor(amax, m, 64));
  __shared__ float wmax[4];
  if ((tid & 63) == 0) wmax[tid >> 6] = amax;
  __syncthreads();
  const float rowmax = fmaxf(fmaxf(wmax[0], wmax[1]), fmaxf(wmax[2], wmax[3]));
  const float inv = (rowmax > 0.f) ? 127.f / rowmax : 0.f;
#pragma unroll
  for (int j = 0; j < 4; ++j) {
    int q0 = (int)rintf(v[j].x * inv);
    int q1 = (int)rintf(v[j].y * inv);
    int q2 = (int)rintf(v[j].z * inv);
    int q3 = (int)rintf(v[j].w * inv);
    unsigned r = ((unsigned)(unsigned char)(char)q0)
               | ((unsigned)(unsigned char)(char)q1 << 8)
               | ((unsigned)(unsigned char)(char)q2 << 16)
               | ((unsigned)(unsigned char)(char)q3 << 24);
    orow[j * 256 + tid] = (int)r;
  }
  if (tid == 0) scale[row] = rowmax * (1.f / 127.f);
}

// ---------------- fragment-read helpers (verified addressing) --------------

__device__ __forceinline__ void fp4_compute(const unsigned char* Asb,
                                            const unsigned char* Bsb,
                                            int wy, int wx, int fr, int swz,
                                            f32x4 (&acc)[4][4]) {
  i32x8 a[4], b[4];
#pragma unroll
  for (int i = 0; i < 4; ++i) {
    i32x4 t = *(const i32x4*)(Asb + (wy * 64 + i * 16 + fr) * 64 + swz);
    a[i] = (i32x8){t[0], t[1], t[2], t[3], 0, 0, 0, 0};   // fp4 reads regs 0..3 only
  }
#pragma unroll
  for (int j = 0; j < 4; ++j) {
    i32x4 t = *(const i32x4*)(Bsb + (wx * 64 + j * 16 + fr) * 64 + swz);
    b[j] = (i32x8){t[0], t[1], t[2], t[3], 0, 0, 0, 0};
  }
#pragma unroll
  for (int i = 0; i < 4; ++i)
#pragma unroll
    for (int j = 0; j < 4; ++j)
      acc[i][j] = __builtin_amdgcn_mfma_scale_f32_16x16x128_f8f6f4(
          a[i], b[j], acc[i][j],
          4, 4,                 // cbsz=fp4(e2m1), blgp=fp4(e2m1)
          0, 0x7f7f7f7f,        // scale_a = 2^0
          0, 0x7f7f7f7f);       // scale_b = 2^0
}

__device__ __forceinline__ void i8_compute(const char* Asb, const char* Bsb,
                                           int wy, int wx, int fr, int swz,
                                           i32x4 (&acc)[4][4]) {
  i32x4 a[4], b[4];
#pragma unroll
  for (int i = 0; i < 4; ++i)
    a[i] = *(const i32x4*)(Asb + (wy * 64 + i * 16 + fr) * 64 + swz);
#pragma unroll
  for (int j = 0; j < 4; ++j)
    b[j] = *(const i32x4*)(Bsb + (wx * 64 + j * 16 + fr) * 64 + swz);
#pragma unroll
  for (int i = 0; i < 4; ++i)
#pragma unroll
    for (int j = 0; j < 4; ++j)
      acc[i][j] = __builtin_amdgcn_mfma_i32_16x16x64_i8(a[i], b[j], acc[i][j], 0, 0, 0);
}

// ---------------------------------------------------------------------------
// Ternary MX-fp4 GEMM, 2-phase double-buffered. C = sign(A @ B^T + bias).
// A [M,2048B] / B [N,2048B] packed fp4. 128x128 tile, K=128/iter (64B rows),
// 32 iters fully unrolled -> immediate-offset global_load_lds.
// EPI=0: packed-fp4 output (layer 1).  EPI=1: i8 output (layer 2).
// ---------------------------------------------------------------------------
template <int EPI>
__global__ __launch_bounds__(256)
void gemm_fp4(const unsigned char* __restrict__ A,
              const unsigned char* __restrict__ B,
              const float* __restrict__ bias,
              unsigned* __restrict__ Cp4,
              char* __restrict__ Ci8,
              int ldc)
{
  constexpr int KB  = 2048;          // K=4096 fp4 -> 2048 bytes/row
  constexpr int NIT = KB / 64;       // 32 K-iters

  __shared__ unsigned char As[2][128 * 64];   // 2 x 8 KB double buffer
  __shared__ unsigned char Bs[2][128 * 64];

  const int tid  = threadIdx.x;
  const int lane = tid & 63;
  const int wid  = tid >> 6;
  const int wy   = wid >> 1;
  const int wx   = wid & 1;

  // bijective XCD swizzle (nwg % 8 == 0): same-XCD blocks share A panels
  const int nwg  = gridDim.x * gridDim.y;
  const int flat = blockIdx.y * gridDim.x + blockIdx.x;
  const int swzb = (flat & 7) * (nwg >> 3) + (flat >> 3);
  const int m0   = (swzb / gridDim.x) * BM;
  const int n0   = (swzb % gridDim.x) * BN;

  // staging: thread t fills slots t (rows 0..63) and t+256 (rows 64..127)
  const int r1 = tid >> 2;
  const int r2 = r1 + 64;
  const int c1 = (tid & 3) ^ ((r1 >> 1) & 3);
  const int c2 = (tid & 3) ^ ((r2 >> 1) & 3);
  const unsigned char* Ag1 = A + (size_t)(m0 + r1) * KB + c1 * 16;
  const unsigned char* Ag2 = A + (size_t)(m0 + r2) * KB + c2 * 16;
  const unsigned char* Bg1 = B + (size_t)(n0 + r1) * KB + c1 * 16;
  const unsigned char* Bg2 = B + (size_t)(n0 + r2) * KB + c2 * 16;

  f32x4 acc[4][4];
#pragma unroll
  for (int i = 0; i < 4; ++i)
#pragma unroll
    for (int j = 0; j < 4; ++j)
      acc[i][j] = (f32x4){0.f, 0.f, 0.f, 0.f};

  const int fr  = lane & 15;
  const int kc  = lane >> 4;
  const int swz = (kc ^ ((fr >> 1) & 3)) * 16;

#define STAGE_FP4(buf, k0)                                   \
  do {                                                       \
    async_copy16(Ag1 + (k0), &As[buf][tid * 16]);            \
    async_copy16(Ag2 + (k0), &As[buf][(tid + 256) * 16]);    \
    async_copy16(Bg1 + (k0), &Bs[buf][tid * 16]);            \
    async_copy16(Bg2 + (k0), &Bs[buf][(tid + 256) * 16]);    \
  } while (0)

  STAGE_FP4(0, 0);
  __syncthreads();                       // buf0 ready

#pragma unroll
  for (int it = 0; it < NIT - 1; ++it) {
    const int cur = it & 1;
    STAGE_FP4(cur ^ 1, (it + 1) * 64);   // prefetch next tile (other buffer)
    fp4_compute(As[cur], Bs[cur], wy, wx, fr, swz, acc);
    __syncthreads();                     // drains vmcnt -> next buf ready,
  }                                      // and all reads of cur done
  fp4_compute(As[(NIT - 1) & 1], Bs[(NIT - 1) & 1], wy, wx, fr, swz, acc);
#undef STAGE_FP4

  // C/D layout: col=lane&15, row=(lane>>4)*4+reg
  const int ccol = lane & 15;
  const int crow = (lane >> 4) * 4;

  if (EPI == 1) {
#pragma unroll
    for (int i = 0; i < 4; ++i) {
      const int m = m0 + wy * 64 + i * 16 + crow;
#pragma unroll
      for (int j = 0; j < 4; ++j) {
        const int n = n0 + wx * 64 + j * 16 + ccol;
        const float bv = bias[n];
#pragma unroll
        for (int r = 0; r < 4; ++r)
          Ci8[(size_t)(m + r) * ldc + n] = sign8(acc[i][j][r] + bv);
      }
    }
  } else {
    // packed-fp4 output: 3-round shfl_xor nibble compaction.
    // byte c holds elements 2c (lo nibble), 2c+1 (hi) -- identical convention
    // to sign_pack_fp4, so layer 2 consumes a1p with the same fragment code.
#pragma unroll
    for (int i = 0; i < 4; ++i) {
      const int m = m0 + wy * 64 + i * 16 + crow;
#pragma unroll
      for (int r = 0; r < 4; ++r) {
        unsigned w32[4];
#pragma unroll
        for (int j = 0; j < 4; ++j) {
          const int n = n0 + wx * 64 + j * 16 + ccol;
          unsigned nb = nib4(acc[i][j][r] + bias[n]);
          unsigned pb = nb | (((unsigned)__shfl_xor((int)nb, 1)) << 4);  // ccol even
          unsigned w  = pb | (((unsigned)__shfl_xor((int)pb, 2)) << 8);  // ccol%4==0
          w32[j]      = w  | (((unsigned)__shfl_xor((int)w,  4)) << 16); // ccol%8==0
        }
        if ((ccol & 7) == 0) {
          const size_t rowb = (size_t)(m + r) * (ldc >> 3);  // row in u32s
#pragma unroll
          for (int j = 0; j < 4; ++j)
            Cp4[rowb + ((n0 + wx * 64 + j * 16 + ccol) >> 3)] = w32[j];
        }
      }
    }
  }
}

// ---------------------------------------------------------------------------
// i8 GEMM for layer 3: Cf = (A_i8 @ B_i8^T) * scale[n] + bias[n], n < nvalid.
// Same 2-phase double-buffered structure; K=64 i8 per iter, 64 iters
// (unroll 8 keeps global_load_lds offsets in immediate range).
// |acc| <= 4096*127 << 2^31 -> exact integer accumulation.
// ---------------------------------------------------------------------------
__global__ __launch_bounds__(256)
void gemm_i8(const char* __restrict__ A,
             const char* __restrict__ B,
             const float* __restrict__ scale,
             const float* __restrict__ bias,
             float* __restrict__ Cf,
             int ldc, int nvalid)
{
  constexpr int KB  = 4096;          // K=4096 i8 bytes/row
  constexpr int NIT = KB / 64;       // 64 K-iters

  __shared__ char As[2][128 * 64];
  __shared__ char Bs[2][128 * 64];

  const int tid  = threadIdx.x;
  const int lane = tid & 63;
  const int wid  = tid >> 6;
  const int wy   = wid >> 1;
  const int wx   = wid & 1;

  const int nwg  = gridDim.x * gridDim.y;
  const int flat = blockIdx.y * gridDim.x + blockIdx.x;
  const int swzb = (flat & 7) * (nwg >> 3) + (flat >> 3);
  const int m0   = (swzb / gridDim.x) * BM;
  const int n0   = (swzb % gridDim.x) * BN;

  const int r1 = tid >> 2;
  const int r2 = r1 + 64;
  const int c1 = (tid & 3) ^ ((r1 >> 1) & 3);
  const int c2 = (tid & 3) ^ ((r2 >> 1) & 3);
  const char* Ag1 = A + (size_t)(m0 + r1) * KB + c1 * 16;
  const char* Ag2 = A + (size_t)(m0 + r2) * KB + c2 * 16;
  const char* Bg1 = B + (size_t)(n0 + r1) * KB + c1 * 16;
  const char* Bg2 = B + (size_t)(n0 + r2) * KB + c2 * 16;

  i32x4 acc[4][4];
#pragma unroll
  for (int i = 0; i < 4; ++i)
#pragma unroll
    for (int j = 0; j < 4; ++j)
      acc[i][j] = (i32x4){0, 0, 0, 0};

  const int fr  = lane & 15;
  const int kc  = lane >> 4;
  const int swz = (kc ^ ((fr >> 1) & 3)) * 16;

#define STAGE_I8(buf, k0)                                    \
  do {                                                       \
    async_copy16(Ag1 + (k0), &As[buf][tid * 16]);            \
    async_copy16(Ag2 + (k0), &As[buf][(tid + 256) * 16]);    \
    async_copy16(Bg1 + (k0), &Bs[buf][tid * 16]);            \
    async_copy16(Bg2 + (k0), &Bs[buf][(tid + 256) * 16]);    \
  } while (0)

  STAGE_I8(0, 0);
  __syncthreads();

#pragma unroll 8
  for (int it = 0; it < NIT - 1; ++it) {
    const int cur = it & 1;
    STAGE_I8(cur ^ 1, (it + 1) * 64);
    i8_compute(As[cur], Bs[cur], wy, wx, fr, swz, acc);
    __syncthreads();
  }
  i8_compute(As[(NIT - 1) & 1], Bs[(NIT - 1) & 1], wy, wx, fr, swz, acc);
#undef STAGE_I8

  const int ccol = lane & 15;
  const int crow = (lane >> 4) * 4;
#pragma unroll
  for (int i = 0; i < 4; ++i) {
    const int m = m0 + wy * 64 + i * 16 + crow;
#pragma unroll
    for (int j = 0; j < 4; ++j) {
      const int n = n0 + wx * 64 + j * 16 + ccol;
      if (n >= nvalid) continue;
      const float sv = scale[n];
      const float bv = bias[n];
#pragma unroll
      for (int r = 0; r < 4; ++r)
        Cf[(size_t)(m + r) * ldc + n] = (float)acc[i][j][r] * sv + bv;
    }
  }
}

extern "C" void kernel_launch(void* const* d_in, const int* in_sizes, int n_in,
                              void* d_out, int out_size, void* d_ws, size_t ws_size,
                              hipStream_t stream) {
  const float* x  = (const float*)d_in[0];   // [8192,4096]
  const float* w1 = (const float*)d_in[1];   // [4096,4096]
  const float* b1 = (const float*)d_in[2];   // [4096]
  const float* w2 = (const float*)d_in[3];   // [4096,4096]
  const float* b2 = (const float*)d_in[4];   // [4096]
  const float* w3 = (const float*)d_in[5];   // [1000,4096]
  const float* b3 = (const float*)d_in[6];   // [1000]

  const int Mb = 8192, H = 4096, C = 1000, Cpad = 1024;

  // workspace layout (88 MB used):
  //   [0,16M)    xp   fp4-packed sign(x)       [8192,2048B]
  //   [16,24M)   w1p  fp4-packed sign(w1)      [4096,2048B]
  //   [24,32M)   w2p  fp4-packed sign(w2)      [4096,2048B]
  //   [32,36M)   w3q  i8 [1024,4096] padded
  //   [36M,+4K)  s3   fp32 per-row scales [1024]
  //   [40,56M)   a1p  fp4-packed a1            [8192,2048B]  (direct from L1)
  //   [56,88M)   a2   i8   [8192,4096]
  char* ws = (char*)d_ws;
  unsigned* xp  = (unsigned*)(ws);
  unsigned* w1p = (unsigned*)(ws + (size_t)16777216);
  unsigned* w2p = (unsigned*)(ws + (size_t)25165824);
  char*     w3q = ws + (size_t)33554432;
  float*    s3  = (float*)(ws + (size_t)37748736);
  unsigned* a1p = (unsigned*)(ws + (size_t)41943040);
  char*     a2  = ws + (size_t)58720256;

  sign_pack_fp4<<<(Mb * H / 8 + 255) / 256, 256, 0, stream>>>(x,  xp,  Mb * H / 8);
  sign_pack_fp4<<<(H * H / 8 + 255) / 256, 256, 0, stream>>>(w1, w1p, H * H / 8);
  sign_pack_fp4<<<(H * H / 8 + 255) / 256, 256, 0, stream>>>(w2, w2p, H * H / 8);
  w3_quant<<<Cpad, 256, 0, stream>>>(w3, w3q, s3, C);

  dim3 blk(256);
  // layer 1: a1p = pack_fp4(sign(sign(x) @ sign(w1)^T + b1))   [exact, fused]
  gemm_fp4<0><<<dim3(H / BN, Mb / BM), blk, 0, stream>>>(
      (const unsigned char*)xp, (const unsigned char*)w1p, b1, a1p, nullptr, H);
  // layer 2: a2 = sign(a1 @ sign(w2)^T + b2)                    [exact, i8 out]
  gemm_fp4<1><<<dim3(H / BN, Mb / BM), blk, 0, stream>>>(
      (const unsigned char*)a1p, (const unsigned char*)w2p, b2, nullptr, a2, H);
  // layer 3: out = a2 @ w3q^T * s3 + b3                         [i8 exact-A]
  gemm_i8<<<dim3(Cpad / BN, Mb / BM), blk, 0, stream>>>(
      a2, w3q, s3, b3, (float*)d_out, C, C);
}

// Round 3
// 552.136 us; speedup vs baseline: 1.1816x; 1.1816x over previous
//
#include <hip/hip_runtime.h>
#include <hip/hip_bf16.h>

// SimpleBNN: out = sign(sign(sign(x)@sign(w1)T + b1) @ sign(w2)T + b2) @ w3T + b3
// Layers 1-2: exact ternary GEMM via MX-fp4 MFMA (K=128/inst, scale=1.0):
//   fp4 e2m1 represents {-1,0,+1} exactly; products +-1, |sums|<=4096 << 2^24
//   with fp32 accumulation -> bit-exact vs the numpy reference.
// Layer 3: exact ternary A (i8) x per-row-quantized i8 w3 (absmax ~1.5e-2).
//
// Round-3: REVERT the round-2 double-buffer/unroll experiment (occupancy
// collapsed 29%->10%, VGPR 84->176, FETCH 77->271 MB -> 2.2x slower; exactly
// the documented m99/m100/m132 null for explicit dbuf at the 128-tile
// 2-barrier structure). Restore the verified round-1 loop (single-buffered,
// runtime-K, two __syncthreads per K-iter, no XCD swizzle) and KEEP the two
// orthogonal wins:
//   * layer-1 epilogue emits packed fp4 directly (3x shfl_xor nibble
//     compaction, verified bit-identical in round 2) -> repack kernel and
//     a1-i8 round trip eliminated.
//   * layer-3 i8 GEMM (v_mfma_i32_16x16x64_i8, per-row-quantized w3).
//
// LDS tiles use the verified XOR-swizzled layout (16B granules):
//   slot s in [0,512) <-> (row = s>>2, chunk c = (s&3) ^ ((row>>1)&3))
// staging stays coalesced (16 x 64B lines/wave) and fragment ds_read_b128s
// are conflict-free (2-way aliasing = free, m136). Any consistent within-row
// k-permutation applied to both A and B cancels in A@B^T.

typedef __attribute__((ext_vector_type(4))) float f32x4;
typedef __attribute__((ext_vector_type(4))) int   i32x4;
typedef __attribute__((ext_vector_type(8))) int   i32x8;

#define BM 128
#define BN 128

__device__ __forceinline__ void async_copy16(const void* g, void* l) {
  __builtin_amdgcn_global_load_lds(
      (const __attribute__((address_space(1))) void*)g,
      (__attribute__((address_space(3))) void*)l,
      16, 0, 0);
}

__device__ __forceinline__ char sign8(float v) {
  return (v > 0.f) ? (char)1 : ((v < 0.f) ? (char)-1 : (char)0);
}
// fp4 e2m1 nibble for sign: +1 -> 0x2, -1 -> 0xA, 0 -> 0x0
__device__ __forceinline__ unsigned nib4(float v) {
  return (v > 0.f) ? 0x2u : ((v < 0.f) ? 0xAu : 0x0u);
}

// fp32 -> packed fp4 sign, 8 elems/thread (4B coalesced stores)
__global__ void sign_pack_fp4(const float* __restrict__ in, unsigned* __restrict__ out, int n8) {
  int i = blockIdx.x * blockDim.x + threadIdx.x;
  if (i >= n8) return;
  const float4* p = (const float4*)in + (size_t)i * 2;
  float4 v0 = p[0], v1 = p[1];
  unsigned b0 = nib4(v0.x) | (nib4(v0.y) << 4);
  unsigned b1 = nib4(v0.z) | (nib4(v0.w) << 4);
  unsigned b2 = nib4(v1.x) | (nib4(v1.y) << 4);
  unsigned b3 = nib4(v1.z) | (nib4(v1.w) << 4);
  out[i] = b0 | (b1 << 8) | (b2 << 16) | (b3 << 24);
}

// w3 [1000,4096] fp32 -> i8 [1024,4096] with per-row scale s[row]=rowmax/127;
// rows >= rows_valid zero-filled with scale 0. One 256-thread block per row.
__global__ __launch_bounds__(256)
void w3_quant(const float* __restrict__ in, char* __restrict__ out,
              float* __restrict__ scale, int rows_valid) {
  const int row = blockIdx.x;
  const int tid = threadIdx.x;
  int* orow = (int*)(out + (size_t)row * 4096);
  if (row >= rows_valid) {
#pragma unroll
    for (int j = 0; j < 4; ++j) orow[j * 256 + tid] = 0;
    if (tid == 0) scale[row] = 0.f;
    return;
  }
  const float4* p = (const float4*)(in + (size_t)row * 4096);
  float4 v[4];
  float amax = 0.f;
#pragma unroll
  for (int j = 0; j < 4; ++j) {
    v[j] = p[j * 256 + tid];
    amax = fmaxf(amax, fmaxf(fmaxf(fabsf(v[j].x), fabsf(v[j].y)),
                             fmaxf(fabsf(v[j].z), fabsf(v[j].w))));
  }
#pragma unroll
  for (int m = 32; m >= 1; m >>= 1)
    amax = fmaxf(amax, __shfl_xor(amax, m, 64));
  __shared__ float wmax[4];
  if ((tid & 63) == 0) wmax[tid >> 6] = amax;
  __syncthreads();
  const float rowmax = fmaxf(fmaxf(wmax[0], wmax[1]), fmaxf(wmax[2], wmax[3]));
  const float inv = (rowmax > 0.f) ? 127.f / rowmax : 0.f;
#pragma unroll
  for (int j = 0; j < 4; ++j) {
    int q0 = (int)rintf(v[j].x * inv);
    int q1 = (int)rintf(v[j].y * inv);
    int q2 = (int)rintf(v[j].z * inv);
    int q3 = (int)rintf(v[j].w * inv);
    unsigned r = ((unsigned)(unsigned char)(char)q0)
               | ((unsigned)(unsigned char)(char)q1 << 8)
               | ((unsigned)(unsigned char)(char)q2 << 16)
               | ((unsigned)(unsigned char)(char)q3 << 24);
    orow[j * 256 + tid] = (int)r;
  }
  if (tid == 0) scale[row] = rowmax * (1.f / 127.f);
}

// ---------------------------------------------------------------------------
// Ternary MX-fp4 GEMM (round-1 verified structure): single-buffered LDS,
// one barrier-pair per K=128 step, mfma_scale_f32_16x16x128_f8f6f4
// (cbsz=blgp=4 -> fp4, scales 0x7F = 2^0). 4 waves x 4x4 16x16 tiles.
// Fragment: lane holds 16B = 32 fp4 of k-quadrant (lane>>4)*32, row fr.
// EPI=0: packed-fp4 output (layer 1).  EPI=1: i8 output (layer 2).
// ---------------------------------------------------------------------------
template <int EPI>
__global__ __launch_bounds__(256)
void gemm_fp4(const unsigned char* __restrict__ A,
              const unsigned char* __restrict__ B,
              const float* __restrict__ bias,
              unsigned* __restrict__ Cp4,
              char* __restrict__ Ci8,
              int Kb, int ldc)
{
  __shared__ unsigned char As[128 * 64];   // 8 KB, swizzled 16B granules
  __shared__ unsigned char Bs[128 * 64];   // 8 KB

  const int tid  = threadIdx.x;
  const int lane = tid & 63;
  const int wid  = tid >> 6;
  const int wy   = wid >> 1;
  const int wx   = wid & 1;

  const int m0 = blockIdx.y * BM;
  const int n0 = blockIdx.x * BN;

  // staging: thread t fills slots t (rows 0..63) and t+256 (rows 64..127)
  const int r1 = tid >> 2;
  const int r2 = r1 + 64;
  const int c1 = (tid & 3) ^ ((r1 >> 1) & 3);
  const int c2 = (tid & 3) ^ ((r2 >> 1) & 3);
  const unsigned char* Ag1 = A + (size_t)(m0 + r1) * Kb + c1 * 16;
  const unsigned char* Ag2 = A + (size_t)(m0 + r2) * Kb + c2 * 16;
  const unsigned char* Bg1 = B + (size_t)(n0 + r1) * Kb + c1 * 16;
  const unsigned char* Bg2 = B + (size_t)(n0 + r2) * Kb + c2 * 16;
  unsigned char* Asl1 = As + tid * 16;
  unsigned char* Asl2 = As + (tid + 256) * 16;
  unsigned char* Bsl1 = Bs + tid * 16;
  unsigned char* Bsl2 = Bs + (tid + 256) * 16;

  f32x4 acc[4][4];
#pragma unroll
  for (int i = 0; i < 4; ++i)
#pragma unroll
    for (int j = 0; j < 4; ++j)
      acc[i][j] = (f32x4){0.f, 0.f, 0.f, 0.f};

  const int fr  = lane & 15;                      // row within 16-tile
  const int kc  = lane >> 4;                      // k-quadrant 0..3
  const int swz = (kc ^ ((fr >> 1) & 3)) * 16;    // swizzled granule byte offset

  for (int k0 = 0; k0 < Kb; k0 += 64) {           // 64 bytes = 128 fp4 per iter
    async_copy16(Ag1 + k0, Asl1);
    async_copy16(Ag2 + k0, Asl2);
    async_copy16(Bg1 + k0, Bsl1);
    async_copy16(Bg2 + k0, Bsl2);
    __syncthreads();   // drains vmcnt -> staged data visible

    i32x8 a[4], b[4];
#pragma unroll
    for (int i = 0; i < 4; ++i) {
      i32x4 t = *(const i32x4*)(As + (wy * 64 + i * 16 + fr) * 64 + swz);
      a[i] = (i32x8){t[0], t[1], t[2], t[3], 0, 0, 0, 0};   // fp4 reads regs 0..3 only
    }
#pragma unroll
    for (int j = 0; j < 4; ++j) {
      i32x4 t = *(const i32x4*)(Bs + (wx * 64 + j * 16 + fr) * 64 + swz);
      b[j] = (i32x8){t[0], t[1], t[2], t[3], 0, 0, 0, 0};
    }

#pragma unroll
    for (int i = 0; i < 4; ++i)
#pragma unroll
      for (int j = 0; j < 4; ++j)
        acc[i][j] = __builtin_amdgcn_mfma_scale_f32_16x16x128_f8f6f4(
            a[i], b[j], acc[i][j],
            4, 4,                 // cbsz=fp4(e2m1), blgp=fp4(e2m1)
            0, 0x7f7f7f7f,        // scale_a = 2^0
            0, 0x7f7f7f7f);       // scale_b = 2^0
    __syncthreads();
  }

  // C/D layout (shape-determined, m121-m128): col=lane&15, row=(lane>>4)*4+reg
  const int ccol = lane & 15;
  const int crow = (lane >> 4) * 4;

  if (EPI == 1) {
    // i8 ternary output (layer 2)
#pragma unroll
    for (int i = 0; i < 4; ++i) {
      const int m = m0 + wy * 64 + i * 16 + crow;
#pragma unroll
      for (int j = 0; j < 4; ++j) {
        const int n = n0 + wx * 64 + j * 16 + ccol;
        const float bv = bias[n];
#pragma unroll
        for (int r = 0; r < 4; ++r)
          Ci8[(size_t)(m + r) * ldc + n] = sign8(acc[i][j][r] + bv);
      }
    }
  } else {
    // packed-fp4 output (layer 1): 3-round shfl_xor nibble compaction.
    // byte c holds elements 2c (lo nibble), 2c+1 (hi) -- identical convention
    // to sign_pack_fp4, so layer 2 consumes a1p with the same fragment code.
    // Verified bit-identical in round 2 (absmax unchanged).
#pragma unroll
    for (int i = 0; i < 4; ++i) {
      const int m = m0 + wy * 64 + i * 16 + crow;
#pragma unroll
      for (int r = 0; r < 4; ++r) {
        unsigned w32[4];
#pragma unroll
        for (int j = 0; j < 4; ++j) {
          const int n = n0 + wx * 64 + j * 16 + ccol;
          unsigned nb = nib4(acc[i][j][r] + bias[n]);
          unsigned pb = nb | (((unsigned)__shfl_xor((int)nb, 1)) << 4);  // ccol even
          unsigned w  = pb | (((unsigned)__shfl_xor((int)pb, 2)) << 8);  // ccol%4==0
          w32[j]      = w  | (((unsigned)__shfl_xor((int)w,  4)) << 16); // ccol%8==0
        }
        if ((ccol & 7) == 0) {
          const size_t rowb = (size_t)(m + r) * (ldc >> 3);  // row in u32s
#pragma unroll
          for (int j = 0; j < 4; ++j)
            Cp4[rowb + ((n0 + wx * 64 + j * 16 + ccol) >> 3)] = w32[j];
        }
      }
    }
  }
}

// ---------------------------------------------------------------------------
// i8 GEMM for layer 3 (round-1 verified): Cf = (A @ B^T) * scale[n] + bias[n],
// n < nvalid. A [M,K] i8 ternary (exact), B [N,K] i8 (quantized w3).
// Same single-buffered 128x128 swizzled-LDS structure; K=64 i8 per stage,
// v_mfma_i32_16x16x64_i8. |acc| <= 4096*127 << 2^31 -> exact.
// ---------------------------------------------------------------------------
__global__ __launch_bounds__(256)
void gemm_i8(const char* __restrict__ A,
             const char* __restrict__ B,
             const float* __restrict__ scale,
             const float* __restrict__ bias,
             float* __restrict__ Cf,
             int Kb, int ldc, int nvalid)
{
  __shared__ char As[128 * 64];
  __shared__ char Bs[128 * 64];

  const int tid  = threadIdx.x;
  const int lane = tid & 63;
  const int wid  = tid >> 6;
  const int wy   = wid >> 1;
  const int wx   = wid & 1;

  const int m0 = blockIdx.y * BM;
  const int n0 = blockIdx.x * BN;

  const int r1 = tid >> 2;
  const int r2 = r1 + 64;
  const int c1 = (tid & 3) ^ ((r1 >> 1) & 3);
  const int c2 = (tid & 3) ^ ((r2 >> 1) & 3);
  const char* Ag1 = A + (size_t)(m0 + r1) * Kb + c1 * 16;
  const char* Ag2 = A + (size_t)(m0 + r2) * Kb + c2 * 16;
  const char* Bg1 = B + (size_t)(n0 + r1) * Kb + c1 * 16;
  const char* Bg2 = B + (size_t)(n0 + r2) * Kb + c2 * 16;
  char* Asl1 = As + tid * 16;
  char* Asl2 = As + (tid + 256) * 16;
  char* Bsl1 = Bs + tid * 16;
  char* Bsl2 = Bs + (tid + 256) * 16;

  i32x4 acc[4][4];
#pragma unroll
  for (int i = 0; i < 4; ++i)
#pragma unroll
    for (int j = 0; j < 4; ++j)
      acc[i][j] = (i32x4){0, 0, 0, 0};

  const int fr  = lane & 15;
  const int kc  = lane >> 4;
  const int swz = (kc ^ ((fr >> 1) & 3)) * 16;

  for (int k0 = 0; k0 < Kb; k0 += 64) {           // 64 i8 = K-step 64
    async_copy16(Ag1 + k0, Asl1);
    async_copy16(Ag2 + k0, Asl2);
    async_copy16(Bg1 + k0, Bsl1);
    async_copy16(Bg2 + k0, Bsl2);
    __syncthreads();

    i32x4 a[4], b[4];
#pragma unroll
    for (int i = 0; i < 4; ++i)
      a[i] = *(const i32x4*)(As + (wy * 64 + i * 16 + fr) * 64 + swz);
#pragma unroll
    for (int j = 0; j < 4; ++j)
      b[j] = *(const i32x4*)(Bs + (wx * 64 + j * 16 + fr) * 64 + swz);

#pragma unroll
    for (int i = 0; i < 4; ++i)
#pragma unroll
      for (int j = 0; j < 4; ++j)
        acc[i][j] = __builtin_amdgcn_mfma_i32_16x16x64_i8(a[i], b[j], acc[i][j], 0, 0, 0);
    __syncthreads();
  }

  const int ccol = lane & 15;
  const int crow = (lane >> 4) * 4;
#pragma unroll
  for (int i = 0; i < 4; ++i) {
    const int m = m0 + wy * 64 + i * 16 + crow;
#pragma unroll
    for (int j = 0; j < 4; ++j) {
      const int n = n0 + wx * 64 + j * 16 + ccol;
      if (n >= nvalid) continue;
      const float sv = scale[n];
      const float bv = bias[n];
#pragma unroll
      for (int r = 0; r < 4; ++r)
        Cf[(size_t)(m + r) * ldc + n] = (float)acc[i][j][r] * sv + bv;
    }
  }
}

extern "C" void kernel_launch(void* const* d_in, const int* in_sizes, int n_in,
                              void* d_out, int out_size, void* d_ws, size_t ws_size,
                              hipStream_t stream) {
  const float* x  = (const float*)d_in[0];   // [8192,4096]
  const float* w1 = (const float*)d_in[1];   // [4096,4096]
  const float* b1 = (const float*)d_in[2];   // [4096]
  const float* w2 = (const float*)d_in[3];   // [4096,4096]
  const float* b2 = (const float*)d_in[4];   // [4096]
  const float* w3 = (const float*)d_in[5];   // [1000,4096]
  const float* b3 = (const float*)d_in[6];   // [1000]

  const int Mb = 8192, H = 4096, C = 1000, Cpad = 1024;
  const int Kb = H / 2;                      // packed fp4 bytes per row

  // workspace layout (88 MB used):
  //   [0,16M)    xp   fp4-packed sign(x)       [8192,2048B]
  //   [16,24M)   w1p  fp4-packed sign(w1)      [4096,2048B]
  //   [24,32M)   w2p  fp4-packed sign(w2)      [4096,2048B]
  //   [32,36M)   w3q  i8 [1024,4096] padded
  //   [36M,+4K)  s3   fp32 per-row scales [1024]
  //   [40,56M)   a1p  fp4-packed a1            [8192,2048B]  (direct from L1)
  //   [56,88M)   a2   i8   [8192,4096]
  char* ws = (char*)d_ws;
  unsigned* xp  = (unsigned*)(ws);
  unsigned* w1p = (unsigned*)(ws + (size_t)16777216);
  unsigned* w2p = (unsigned*)(ws + (size_t)25165824);
  char*     w3q = ws + (size_t)33554432;
  float*    s3  = (float*)(ws + (size_t)37748736);
  unsigned* a1p = (unsigned*)(ws + (size_t)41943040);
  char*     a2  = ws + (size_t)58720256;

  sign_pack_fp4<<<(Mb * H / 8 + 255) / 256, 256, 0, stream>>>(x,  xp,  Mb * H / 8);
  sign_pack_fp4<<<(H * H / 8 + 255) / 256, 256, 0, stream>>>(w1, w1p, H * H / 8);
  sign_pack_fp4<<<(H * H / 8 + 255) / 256, 256, 0, stream>>>(w2, w2p, H * H / 8);
  w3_quant<<<Cpad, 256, 0, stream>>>(w3, w3q, s3, C);

  dim3 blk(256);
  // layer 1: a1p = pack_fp4(sign(sign(x) @ sign(w1)^T + b1))   [exact, fused]
  gemm_fp4<0><<<dim3(H / BN, Mb / BM), blk, 0, stream>>>(
      (const unsigned char*)xp, (const unsigned char*)w1p, b1, a1p, nullptr, Kb, H);
  // layer 2: a2 = sign(a1 @ sign(w2)^T + b2)                    [exact, i8 out]
  gemm_fp4<1><<<dim3(H / BN, Mb / BM), blk, 0, stream>>>(
      (const unsigned char*)a1p, (const unsigned char*)w2p, b2, nullptr, a2, Kb, H);
  // layer 3: out = a2 @ w3q^T * s3 + b3                         [i8 exact-A]
  gemm_i8<<<dim3(Cpad / BN, Mb / BM), blk, 0, stream>>>(
      a2, w3q, s3, b3, (float*)d_out, H, C, C);
}

// Round 4
// 517.815 us; speedup vs baseline: 1.2599x; 1.0663x over previous
//
#include <hip/hip_runtime.h>
#include <hip/hip_bf16.h>

// SimpleBNN: out = sign(sign(sign(x)@sign(w1)T + b1) @ sign(w2)T + b2) @ w3T + b3
// Layers 1-2: exact ternary GEMM via MX-fp4 MFMA (K=128/inst, scale=1.0):
//   fp4 e2m1 represents {-1,0,+1} exactly; products +-1, |sums|<=4096 << 2^24
//   with fp32 accumulation -> bit-exact vs the numpy reference.
// Layer 3: exact ternary A (i8) x per-row-quantized i8 w3 (absmax ~1.5e-2).
//
// Round-4 changes (theory: K-loop is stall-dominated -- each iter exposes a
// full global_load_lds latency + vmcnt(0) drain + 2 barriers vs ~90cy MFMA):
//  * Double the K-step to 128B/row in BOTH GEMMs via TWIN verified 64B
//    sub-tiles (As0/As1, Bs0/Bs1; each uses the byte-identical proven XOR
//    swizzle). Halves the number of barrier-drain exposures (32->16 iters in
//    gemm_fp4, 64->32 in gemm_i8). LDS 16->32KB does NOT cut occupancy:
//    blocks/CU stays VGPR-limited at 3 (LDS limit would be 5). This is NOT
//    m132's failed BK=128 (that was 64KB LDS -> occupancy cut to 2).
//  * Merge the three sign_pack_fp4 launches into one (xp/w1p/w2p are
//    contiguous in workspace) -- two fewer launch gaps.
//  * Keep: fused fp4-pack epilogue in layer 1 (traffic-positive), i8 layer 3.
//  * Still NO explicit dbuf / unroll / XCD swizzle (round-2 regression).
//
// LDS sub-tiles use the verified XOR-swizzled layout (16B granules):
//   slot s in [0,512) <-> (row = s>>2, chunk c = (s&3) ^ ((row>>1)&3))
// staging stays coalesced and fragment ds_read_b128s are conflict-free
// (2-way aliasing = free, m136). Any consistent within-row k-permutation
// applied to both A and B cancels in A@B^T.

typedef __attribute__((ext_vector_type(4))) float f32x4;
typedef __attribute__((ext_vector_type(4))) int   i32x4;
typedef __attribute__((ext_vector_type(8))) int   i32x8;

#define BM 128
#define BN 128

__device__ __forceinline__ void async_copy16(const void* g, void* l) {
  __builtin_amdgcn_global_load_lds(
      (const __attribute__((address_space(1))) void*)g,
      (__attribute__((address_space(3))) void*)l,
      16, 0, 0);
}

__device__ __forceinline__ char sign8(float v) {
  return (v > 0.f) ? (char)1 : ((v < 0.f) ? (char)-1 : (char)0);
}
// fp4 e2m1 nibble for sign: +1 -> 0x2, -1 -> 0xA, 0 -> 0x0
__device__ __forceinline__ unsigned nib4(float v) {
  return (v > 0.f) ? 0x2u : ((v < 0.f) ? 0xAu : 0x0u);
}

// fp32 -> packed fp4 sign for THREE tensors in one launch; outputs land in
// the contiguous xp|w1p|w2p workspace region (out[i] with global index i).
__global__ void sign_pack_fp4_3(const float* __restrict__ x,
                                const float* __restrict__ w1,
                                const float* __restrict__ w2,
                                unsigned* __restrict__ out,
                                int n8x, int n8w) {
  int i = blockIdx.x * blockDim.x + threadIdx.x;
  if (i >= n8x + 2 * n8w) return;
  const float* in;
  int k;
  if (i < n8x)            { in = x;  k = i; }
  else if (i < n8x + n8w) { in = w1; k = i - n8x; }
  else                    { in = w2; k = i - n8x - n8w; }
  const float4* p = (const float4*)in + (size_t)k * 2;
  float4 v0 = p[0], v1 = p[1];
  unsigned b0 = nib4(v0.x) | (nib4(v0.y) << 4);
  unsigned b1 = nib4(v0.z) | (nib4(v0.w) << 4);
  unsigned b2 = nib4(v1.x) | (nib4(v1.y) << 4);
  unsigned b3 = nib4(v1.z) | (nib4(v1.w) << 4);
  out[i] = b0 | (b1 << 8) | (b2 << 16) | (b3 << 24);
}

// w3 [1000,4096] fp32 -> i8 [1024,4096] with per-row scale s[row]=rowmax/127;
// rows >= rows_valid zero-filled with scale 0. One 256-thread block per row.
__global__ __launch_bounds__(256)
void w3_quant(const float* __restrict__ in, char* __restrict__ out,
              float* __restrict__ scale, int rows_valid) {
  const int row = blockIdx.x;
  const int tid = threadIdx.x;
  int* orow = (int*)(out + (size_t)row * 4096);
  if (row >= rows_valid) {
#pragma unroll
    for (int j = 0; j < 4; ++j) orow[j * 256 + tid] = 0;
    if (tid == 0) scale[row] = 0.f;
    return;
  }
  const float4* p = (const float4*)(in + (size_t)row * 4096);
  float4 v[4];
  float amax = 0.f;
#pragma unroll
  for (int j = 0; j < 4; ++j) {
    v[j] = p[j * 256 + tid];
    amax = fmaxf(amax, fmaxf(fmaxf(fabsf(v[j].x), fabsf(v[j].y)),
                             fmaxf(fabsf(v[j].z), fabsf(v[j].w))));
  }
#pragma unroll
  for (int m = 32; m >= 1; m >>= 1)
    amax = fmaxf(amax, __shfl_xor(amax, m, 64));
  __shared__ float wmax[4];
  if ((tid & 63) == 0) wmax[tid >> 6] = amax;
  __syncthreads();
  const float rowmax = fmaxf(fmaxf(wmax[0], wmax[1]), fmaxf(wmax[2], wmax[3]));
  const float inv = (rowmax > 0.f) ? 127.f / rowmax : 0.f;
#pragma unroll
  for (int j = 0; j < 4; ++j) {
    int q0 = (int)rintf(v[j].x * inv);
    int q1 = (int)rintf(v[j].y * inv);
    int q2 = (int)rintf(v[j].z * inv);
    int q3 = (int)rintf(v[j].w * inv);
    unsigned r = ((unsigned)(unsigned char)(char)q0)
               | ((unsigned)(unsigned char)(char)q1 << 8)
               | ((unsigned)(unsigned char)(char)q2 << 16)
               | ((unsigned)(unsigned char)(char)q3 << 24);
    orow[j * 256 + tid] = (int)r;
  }
  if (tid == 0) scale[row] = rowmax * (1.f / 127.f);
}

// ---------------- fragment compute helpers (verified addressing) -----------

__device__ __forceinline__ void fp4_compute(const unsigned char* Asb,
                                            const unsigned char* Bsb,
                                            int wy, int wx, int fr, int swz,
                                            f32x4 (&acc)[4][4]) {
  i32x8 a[4], b[4];
#pragma unroll
  for (int i = 0; i < 4; ++i) {
    i32x4 t = *(const i32x4*)(Asb + (wy * 64 + i * 16 + fr) * 64 + swz);
    a[i] = (i32x8){t[0], t[1], t[2], t[3], 0, 0, 0, 0};   // fp4 reads regs 0..3 only
  }
#pragma unroll
  for (int j = 0; j < 4; ++j) {
    i32x4 t = *(const i32x4*)(Bsb + (wx * 64 + j * 16 + fr) * 64 + swz);
    b[j] = (i32x8){t[0], t[1], t[2], t[3], 0, 0, 0, 0};
  }
#pragma unroll
  for (int i = 0; i < 4; ++i)
#pragma unroll
    for (int j = 0; j < 4; ++j)
      acc[i][j] = __builtin_amdgcn_mfma_scale_f32_16x16x128_f8f6f4(
          a[i], b[j], acc[i][j],
          4, 4,                 // cbsz=fp4(e2m1), blgp=fp4(e2m1)
          0, 0x7f7f7f7f,        // scale_a = 2^0
          0, 0x7f7f7f7f);       // scale_b = 2^0
}

__device__ __forceinline__ void i8_compute(const char* Asb, const char* Bsb,
                                           int wy, int wx, int fr, int swz,
                                           i32x4 (&acc)[4][4]) {
  i32x4 a[4], b[4];
#pragma unroll
  for (int i = 0; i < 4; ++i)
    a[i] = *(const i32x4*)(Asb + (wy * 64 + i * 16 + fr) * 64 + swz);
#pragma unroll
  for (int j = 0; j < 4; ++j)
    b[j] = *(const i32x4*)(Bsb + (wx * 64 + j * 16 + fr) * 64 + swz);
#pragma unroll
  for (int i = 0; i < 4; ++i)
#pragma unroll
    for (int j = 0; j < 4; ++j)
      acc[i][j] = __builtin_amdgcn_mfma_i32_16x16x64_i8(a[i], b[j], acc[i][j], 0, 0, 0);
}

// ---------------------------------------------------------------------------
// Ternary MX-fp4 GEMM: single-buffered LDS, K-step 256 fp4 = 128B/row per
// barrier-pair via twin 64B sub-tiles (16 iters over K=4096). 4 waves x
// 4x4 16x16 tiles, mfma_scale_f32_16x16x128_f8f6f4 (cbsz=blgp=4, scale 2^0).
// EPI=0: packed-fp4 output (layer 1).  EPI=1: i8 output (layer 2).
// ---------------------------------------------------------------------------
template <int EPI>
__global__ __launch_bounds__(256)
void gemm_fp4(const unsigned char* __restrict__ A,
              const unsigned char* __restrict__ B,
              const float* __restrict__ bias,
              unsigned* __restrict__ Cp4,
              char* __restrict__ Ci8,
              int Kb, int ldc)
{
  __shared__ unsigned char As0[128 * 64];   // k bytes [k0,    k0+64)
  __shared__ unsigned char As1[128 * 64];   // k bytes [k0+64, k0+128)
  __shared__ unsigned char Bs0[128 * 64];
  __shared__ unsigned char Bs1[128 * 64];

  const int tid  = threadIdx.x;
  const int lane = tid & 63;
  const int wid  = tid >> 6;
  const int wy   = wid >> 1;
  const int wx   = wid & 1;

  const int m0 = blockIdx.y * BM;
  const int n0 = blockIdx.x * BN;

  // staging: thread t fills slots t (rows 0..63) and t+256 (rows 64..127)
  const int r1 = tid >> 2;
  const int r2 = r1 + 64;
  const int c1 = (tid & 3) ^ ((r1 >> 1) & 3);
  const int c2 = (tid & 3) ^ ((r2 >> 1) & 3);
  const unsigned char* Ag1 = A + (size_t)(m0 + r1) * Kb + c1 * 16;
  const unsigned char* Ag2 = A + (size_t)(m0 + r2) * Kb + c2 * 16;
  const unsigned char* Bg1 = B + (size_t)(n0 + r1) * Kb + c1 * 16;
  const unsigned char* Bg2 = B + (size_t)(n0 + r2) * Kb + c2 * 16;
  const int sl1 = tid * 16;
  const int sl2 = (tid + 256) * 16;

  f32x4 acc[4][4];
#pragma unroll
  for (int i = 0; i < 4; ++i)
#pragma unroll
    for (int j = 0; j < 4; ++j)
      acc[i][j] = (f32x4){0.f, 0.f, 0.f, 0.f};

  const int fr  = lane & 15;                      // row within 16-tile
  const int kc  = lane >> 4;                      // k-quadrant 0..3
  const int swz = (kc ^ ((fr >> 1) & 3)) * 16;    // swizzled granule byte offset

  for (int k0 = 0; k0 < Kb; k0 += 128) {          // 128 bytes = 256 fp4 per iter
    async_copy16(Ag1 + k0,      As0 + sl1);
    async_copy16(Ag1 + k0 + 64, As1 + sl1);
    async_copy16(Ag2 + k0,      As0 + sl2);
    async_copy16(Ag2 + k0 + 64, As1 + sl2);
    async_copy16(Bg1 + k0,      Bs0 + sl1);
    async_copy16(Bg1 + k0 + 64, Bs1 + sl1);
    async_copy16(Bg2 + k0,      Bs0 + sl2);
    async_copy16(Bg2 + k0 + 64, Bs1 + sl2);
    __syncthreads();   // drains vmcnt -> staged data visible

    fp4_compute(As0, Bs0, wy, wx, fr, swz, acc);  // k-half 0
    fp4_compute(As1, Bs1, wy, wx, fr, swz, acc);  // k-half 1
    __syncthreads();
  }

  // C/D layout (shape-determined, m121-m128): col=lane&15, row=(lane>>4)*4+reg
  const int ccol = lane & 15;
  const int crow = (lane >> 4) * 4;

  if (EPI == 1) {
    // i8 ternary output (layer 2)
#pragma unroll
    for (int i = 0; i < 4; ++i) {
      const int m = m0 + wy * 64 + i * 16 + crow;
#pragma unroll
      for (int j = 0; j < 4; ++j) {
        const int n = n0 + wx * 64 + j * 16 + ccol;
        const float bv = bias[n];
#pragma unroll
        for (int r = 0; r < 4; ++r)
          Ci8[(size_t)(m + r) * ldc + n] = sign8(acc[i][j][r] + bv);
      }
    }
  } else {
    // packed-fp4 output (layer 1): 3-round shfl_xor nibble compaction.
    // byte c holds elements 2c (lo nibble), 2c+1 (hi) -- identical convention
    // to sign_pack, so layer 2 consumes a1p with the same fragment code.
    // Verified bit-identical in rounds 2-3 (absmax unchanged).
#pragma unroll
    for (int i = 0; i < 4; ++i) {
      const int m = m0 + wy * 64 + i * 16 + crow;
#pragma unroll
      for (int r = 0; r < 4; ++r) {
        unsigned w32[4];
#pragma unroll
        for (int j = 0; j < 4; ++j) {
          const int n = n0 + wx * 64 + j * 16 + ccol;
          unsigned nb = nib4(acc[i][j][r] + bias[n]);
          unsigned pb = nb | (((unsigned)__shfl_xor((int)nb, 1)) << 4);  // ccol even
          unsigned w  = pb | (((unsigned)__shfl_xor((int)pb, 2)) << 8);  // ccol%4==0
          w32[j]      = w  | (((unsigned)__shfl_xor((int)w,  4)) << 16); // ccol%8==0
        }
        if ((ccol & 7) == 0) {
          const size_t rowb = (size_t)(m + r) * (ldc >> 3);  // row in u32s
#pragma unroll
          for (int j = 0; j < 4; ++j)
            Cp4[rowb + ((n0 + wx * 64 + j * 16 + ccol) >> 3)] = w32[j];
        }
      }
    }
  }
}

// ---------------------------------------------------------------------------
// i8 GEMM for layer 3: Cf = (A @ B^T) * scale[n] + bias[n], n < nvalid.
// A [M,K] i8 ternary (exact), B [N,K] i8 (quantized w3). Twin-sub-tile
// K-step 128 i8 per barrier-pair (32 iters), v_mfma_i32_16x16x64_i8.
// |acc| <= 4096*127 << 2^31 -> exact integer accumulation.
// ---------------------------------------------------------------------------
__global__ __launch_bounds__(256)
void gemm_i8(const char* __restrict__ A,
             const char* __restrict__ B,
             const float* __restrict__ scale,
             const float* __restrict__ bias,
             float* __restrict__ Cf,
             int Kb, int ldc, int nvalid)
{
  __shared__ char As0[128 * 64];
  __shared__ char As1[128 * 64];
  __shared__ char Bs0[128 * 64];
  __shared__ char Bs1[128 * 64];

  const int tid  = threadIdx.x;
  const int lane = tid & 63;
  const int wid  = tid >> 6;
  const int wy   = wid >> 1;
  const int wx   = wid & 1;

  const int m0 = blockIdx.y * BM;
  const int n0 = blockIdx.x * BN;

  const int r1 = tid >> 2;
  const int r2 = r1 + 64;
  const int c1 = (tid & 3) ^ ((r1 >> 1) & 3);
  const int c2 = (tid & 3) ^ ((r2 >> 1) & 3);
  const char* Ag1 = A + (size_t)(m0 + r1) * Kb + c1 * 16;
  const char* Ag2 = A + (size_t)(m0 + r2) * Kb + c2 * 16;
  const char* Bg1 = B + (size_t)(n0 + r1) * Kb + c1 * 16;
  const char* Bg2 = B + (size_t)(n0 + r2) * Kb + c2 * 16;
  const int sl1 = tid * 16;
  const int sl2 = (tid + 256) * 16;

  i32x4 acc[4][4];
#pragma unroll
  for (int i = 0; i < 4; ++i)
#pragma unroll
    for (int j = 0; j < 4; ++j)
      acc[i][j] = (i32x4){0, 0, 0, 0};

  const int fr  = lane & 15;
  const int kc  = lane >> 4;
  const int swz = (kc ^ ((fr >> 1) & 3)) * 16;

  for (int k0 = 0; k0 < Kb; k0 += 128) {          // 128 i8 per iter
    async_copy16(Ag1 + k0,      As0 + sl1);
    async_copy16(Ag1 + k0 + 64, As1 + sl1);
    async_copy16(Ag2 + k0,      As0 + sl2);
    async_copy16(Ag2 + k0 + 64, As1 + sl2);
    async_copy16(Bg1 + k0,      Bs0 + sl1);
    async_copy16(Bg1 + k0 + 64, Bs1 + sl1);
    async_copy16(Bg2 + k0,      Bs0 + sl2);
    async_copy16(Bg2 + k0 + 64, Bs1 + sl2);
    __syncthreads();

    i8_compute(As0, Bs0, wy, wx, fr, swz, acc);   // k-half 0
    i8_compute(As1, Bs1, wy, wx, fr, swz, acc);   // k-half 1
    __syncthreads();
  }

  const int ccol = lane & 15;
  const int crow = (lane >> 4) * 4;
#pragma unroll
  for (int i = 0; i < 4; ++i) {
    const int m = m0 + wy * 64 + i * 16 + crow;
#pragma unroll
    for (int j = 0; j < 4; ++j) {
      const int n = n0 + wx * 64 + j * 16 + ccol;
      if (n >= nvalid) continue;
      const float sv = scale[n];
      const float bv = bias[n];
#pragma unroll
      for (int r = 0; r < 4; ++r)
        Cf[(size_t)(m + r) * ldc + n] = (float)acc[i][j][r] * sv + bv;
    }
  }
}

extern "C" void kernel_launch(void* const* d_in, const int* in_sizes, int n_in,
                              void* d_out, int out_size, void* d_ws, size_t ws_size,
                              hipStream_t stream) {
  const float* x  = (const float*)d_in[0];   // [8192,4096]
  const float* w1 = (const float*)d_in[1];   // [4096,4096]
  const float* b1 = (const float*)d_in[2];   // [4096]
  const float* w2 = (const float*)d_in[3];   // [4096,4096]
  const float* b2 = (const float*)d_in[4];   // [4096]
  const float* w3 = (const float*)d_in[5];   // [1000,4096]
  const float* b3 = (const float*)d_in[6];   // [1000]

  const int Mb = 8192, H = 4096, C = 1000, Cpad = 1024;
  const int Kb = H / 2;                      // packed fp4 bytes per row

  // workspace layout (88 MB used):
  //   [0,16M)    xp   fp4-packed sign(x)       [8192,2048B]   } contiguous:
  //   [16,24M)   w1p  fp4-packed sign(w1)      [4096,2048B]   } one packed
  //   [24,32M)   w2p  fp4-packed sign(w2)      [4096,2048B]   } output region
  //   [32,36M)   w3q  i8 [1024,4096] padded
  //   [36M,+4K)  s3   fp32 per-row scales [1024]
  //   [40,56M)   a1p  fp4-packed a1            [8192,2048B]  (direct from L1)
  //   [56,88M)   a2   i8   [8192,4096]
  char* ws = (char*)d_ws;
  unsigned* xp  = (unsigned*)(ws);
  char*     w3q = ws + (size_t)33554432;
  float*    s3  = (float*)(ws + (size_t)37748736);
  unsigned* a1p = (unsigned*)(ws + (size_t)41943040);
  char*     a2  = ws + (size_t)58720256;
  unsigned* w1p = (unsigned*)(ws + (size_t)16777216);
  unsigned* w2p = (unsigned*)(ws + (size_t)25165824);

  const int n8x = Mb * H / 8;                // 4194304 u32 -> xp is 16MB
  const int n8w = H * H / 8;                 // 2097152 u32 -> w1p/w2p 8MB each
  sign_pack_fp4_3<<<(n8x + 2 * n8w + 255) / 256, 256, 0, stream>>>(
      x, w1, w2, xp, n8x, n8w);
  w3_quant<<<Cpad, 256, 0, stream>>>(w3, w3q, s3, C);

  dim3 blk(256);
  // layer 1: a1p = pack_fp4(sign(sign(x) @ sign(w1)^T + b1))   [exact, fused]
  gemm_fp4<0><<<dim3(H / BN, Mb / BM), blk, 0, stream>>>(
      (const unsigned char*)xp, (const unsigned char*)w1p, b1, a1p, nullptr, Kb, H);
  // layer 2: a2 = sign(a1 @ sign(w2)^T + b2)                    [exact, i8 out]
  gemm_fp4<1><<<dim3(H / BN, Mb / BM), blk, 0, stream>>>(
      (const unsigned char*)a1p, (const unsigned char*)w2p, b2, nullptr, a2, Kb, H);
  // layer 3: out = a2 @ w3q^T * s3 + b3                         [i8 exact-A]
  gemm_i8<<<dim3(Cpad / BN, Mb / BM), blk, 0, stream>>>(
      a2, w3q, s3, b3, (float*)d_out, H, C, C);
}